// Round 17
// baseline (57.522 us; speedup 1.0000x reference)
//
#include <hip/hip_runtime.h>
#include <hip/hip_bf16.h>

#define NN 262144
#define DD 32
#define HH 31
#define KK 21
#define ROWS 256                 // rows per block (2 half-row chunks per thread)
#define FSTRIDE 18               // u32 words per feats row (72 B)
#define CSTRIDE 68               // floats per k in const table {b1[32],w2[32],b2,pad3}
#define REPS 6                   // instrumentation: repeat body to surface counters

typedef __attribute__((ext_vector_type(8))) short bf16x8;
typedef __attribute__((ext_vector_type(4))) float f32x4;
typedef __attribute__((ext_vector_type(2))) unsigned int u32x2;
typedef __attribute__((ext_vector_type(4))) unsigned int u32x4;

static __device__ __forceinline__ unsigned short f2bf(float f) {
    __hip_bfloat16 h = __float2bfloat16(f);      // round-to-nearest-even
    return __builtin_bit_cast(unsigned short, h);
}
static __device__ __forceinline__ unsigned pack2(float lo, float hi) {
    return (unsigned)f2bf(lo) | ((unsigned)f2bf(hi) << 16);
}

// ---------------- Prep: per-lane A-fragment tables + compact const table ----
__global__ __launch_bounds__(64) void prep_kernel(
    const float* __restrict__ W1, const float* __restrict__ b1,
    const float* __restrict__ W2, const float* __restrict__ b2,
    bf16x8* __restrict__ A0tab, bf16x8* __restrict__ A1tab,
    float* __restrict__ gcst)
{
    const int k = (int)blockIdx.x;
    const int lane = (int)threadIdx.x;
    const int lrow = lane & 15, lgrp = lane >> 4;
    const float* __restrict__ W1k = W1 + k * HH * HH;
    const int e0 = lrow, e1 = 16 + lrow;

    bf16x8 A0, A1;
    #pragma unroll
    for (int j = 0; j < 4; ++j) {
        const int d1 = 4 * lgrp + j;
        const int d2 = 16 + 4 * lgrp + j;
        A0[j]     = (short)f2bf(W1k[d1 * HH + e0]);
        A0[4 + j] = (d2 < HH) ? (short)f2bf(W1k[d2 * HH + e0]) : (short)0;
        A1[j]     = (e1 < HH) ? (short)f2bf(W1k[d1 * HH + e1]) : (short)0;
        A1[4 + j] = (e1 < HH && d2 < HH) ? (short)f2bf(W1k[d2 * HH + e1]) : (short)0;
    }
    A0tab[k * 64 + lane] = A0;
    A1tab[k * 64 + lane] = A1;

    for (int i = lane; i < CSTRIDE; i += 64) {
        float v = 0.0f;
        if (i < 32)       { if (i < HH) v = b1[k * HH + i]; }
        else if (i < 64)  { const int e = i - 32; if (e < HH) v = W2[k * HH + e]; }
        else if (i == 64) v = b2[k];
        gcst[k * CSTRIDE + i] = v;
    }
}

// ---------------- Fused (r13 structure), body repeated REPS x ----------------
__global__ __launch_bounds__(256, 4) void fused_kernel(
    const float* __restrict__ x,
    const float* __restrict__ a,
    const float* __restrict__ b,
    const bf16x8* __restrict__ A0tab, const bf16x8* __restrict__ A1tab,
    const float* __restrict__ gcst,
    float* __restrict__ out)
{
    __shared__ unsigned fbf[ROWS * FSTRIDE];                  // 18432 B
    __shared__ __align__(16) float scst[KK * CSTRIDE];        // 5712 B
    __shared__ int cnt[KK];
    __shared__ int rnk[KK];
    __shared__ int sbase[KK];
    __shared__ int tstart[KK + 1];
    __shared__ unsigned short sorted[ROWS];

    const int tid = (int)threadIdx.x;
    const int lane = tid & 63;
    const int wave = tid >> 6;
    const int rowbase = (int)blockIdx.x * ROWS;

    // stage const table once
    for (int i = tid; i < KK * CSTRIDE / 4; i += 256)
        ((f32x4*)scst)[i] = ((const f32x4*)gcst)[i];

    for (int rep = 0; rep < REPS; ++rep) {
        if (tid < KK) { cnt[tid] = 0; rnk[tid] = 0; }
        __syncthreads();                                      // BAR A
        asm volatile("" ::: "memory");                        // force real reloads

        // ---- Phase 1: 2 half-row chunks/thread, 64 B/lane coalesced ----
        const float edges[KK + 1] = {
            0.0f, 0.1f, 0.2f, 0.3f, 0.4f, 0.5f, 0.6f, 0.7f, 0.8f, 0.9f, 1.0f,
            1.1f, 1.2f, 1.3f, 1.4f, 1.5f, 1.6f, 1.7f, 1.8f, 1.9f, 2.0f, 1000.0f
        };
        int kq[2] = {-1, -1};
        #pragma unroll
        for (int i = 0; i < 2; ++i) {
            const int c    = tid + 256 * i;
            const int row  = c >> 1;
            const int half = c & 1;
            const float4* __restrict__ p =
                reinterpret_cast<const float4*>(x) + (size_t)blockIdx.x * (ROWS * DD / 4) + c * 4;
            float4 cc[4];
            #pragma unroll
            for (int j = 0; j < 4; ++j) cc[j] = p[j];

            const float e16 = __shfl(cc[0].x, lane + 1);
            const float t = cc[0].x;

            if (half == 0) {
                int kk = -1;
                #pragma unroll
                for (int j = 0; j < KK; ++j)
                    if (t > edges[j] && t <= edges[j + 1]) kk = j;
                kq[i] = kk;
                if (kk >= 0) atomicAdd(&cnt[kk], 1);
                else out[rowbase + row] = 0.0f;
            }

            unsigned* __restrict__ frow = fbf + row * FSTRIDE + half * 8;
            float f[16];
            if (half == 0) {
                #pragma unroll
                for (int j = 0; j < 15; ++j)
                    f[j] = fmaf(((const float*)cc)[j + 1], a[j], b[j]);
                f[15] = fmaf(e16, a[15], b[15]);
            } else {
                #pragma unroll
                for (int j = 0; j < 15; ++j)
                    f[j] = fmaf(((const float*)cc)[j + 1], a[16 + j], b[16 + j]);
                f[15] = 0.0f;
            }
            #pragma unroll
            for (int s = 0; s < 8; ++s) frow[s] = pack2(f[2 * s], f[2 * s + 1]);
        }
        __syncthreads();                                      // BAR B

        // ---- Phase 2: wave-parallel scan + scatter ----
        if (tid < 64) {
            const int j = tid;
            const int c0 = (j < KK) ? cnt[j] : 0;
            const int t0 = (j < KK) ? ((c0 + 15) >> 4) : 0;
            int sc = c0, st = t0;
            #pragma unroll
            for (int off = 1; off < 32; off <<= 1) {
                const int vc = __shfl_up(sc, off);
                const int vt = __shfl_up(st, off);
                if (j >= off) { sc += vc; st += vt; }
            }
            if (j < KK) { sbase[j] = sc - c0; tstart[j] = st - t0; }
            if (j == KK) tstart[KK] = st;
        }
        __syncthreads();                                      // BAR C
        #pragma unroll
        for (int i = 0; i < 2; ++i) {
            const int c = tid + 256 * i;
            if (!(c & 1) && kq[i] >= 0) {
                const int rr = atomicAdd(&rnk[kq[i]], 1);
                sorted[sbase[kq[i]] + rr] = (unsigned short)(c >> 1);
            }
        }
        __syncthreads();                                      // BAR D

        // ---- Phase 3: software-pipelined MFMA tiles ----
        const int lrow = lane & 15;
        const int lgrp = lane >> 4;

        const int NT = tstart[KK];
        const int ts_l = tstart[(lane <= KK) ? lane : KK];

        int tix = wave;
        int k0 = 0, cn0 = 0, rl0 = 0, R0 = 0;
        bf16x8 A0c = {}, A1c = {}, Bc = {};

        if (tix < NT) {
            const unsigned long long m = __ballot(ts_l <= tix);
            k0 = __builtin_amdgcn_readfirstlane(__popcll(m) - 1);
            cn0 = cnt[k0];
            rl0 = (tix - tstart[k0]) * 16 + lrow;
            R0 = sorted[sbase[k0] + ((rl0 < cn0) ? rl0 : 0)];
            const unsigned* __restrict__ fr = fbf + R0 * FSTRIDE;
            const u32x2 wlo = *(const u32x2*)(fr + 2 * lgrp);
            const u32x2 whi = *(const u32x2*)(fr + 8 + 2 * lgrp);
            u32x4 bw; bw[0] = wlo[0]; bw[1] = wlo[1]; bw[2] = whi[0]; bw[3] = whi[1];
            Bc = __builtin_bit_cast(bf16x8, bw);
            A0c = A0tab[k0 * 64 + lane];
            A1c = A1tab[k0 * 64 + lane];
        }

        while (tix < NT) {
            const int nxt = tix + 4;
            const int pt = (nxt < NT) ? nxt : tix;
            const unsigned long long m = __ballot(ts_l <= pt);
            const int k1 = __builtin_amdgcn_readfirstlane(__popcll(m) - 1);
            const int cn1 = cnt[k1];
            const int rl1 = (pt - tstart[k1]) * 16 + lrow;
            const int R1 = sorted[sbase[k1] + ((rl1 < cn1) ? rl1 : 0)];
            const unsigned* __restrict__ frn = fbf + R1 * FSTRIDE;
            const u32x2 nlo = *(const u32x2*)(frn + 2 * lgrp);
            const u32x2 nhi = *(const u32x2*)(frn + 8 + 2 * lgrp);
            u32x4 nw; nw[0] = nlo[0]; nw[1] = nlo[1]; nw[2] = nhi[0]; nw[3] = nhi[1];
            const bf16x8 Bn = __builtin_bit_cast(bf16x8, nw);
            const bf16x8 A0n = A0tab[k1 * 64 + lane];
            const bf16x8 A1n = A1tab[k1 * 64 + lane];

            const float* __restrict__ cp = scst + k0 * CSTRIDE;
            const f32x4 cb0 = *(const f32x4*)(cp + 4 * lgrp);
            const f32x4 cb1 = *(const f32x4*)(cp + 16 + 4 * lgrp);
            const f32x4 cw0 = *(const f32x4*)(cp + 32 + 4 * lgrp);
            const f32x4 cw1 = *(const f32x4*)(cp + 48 + 4 * lgrp);
            const float b2k = cp[64];

            f32x4 acc0 = {0.0f, 0.0f, 0.0f, 0.0f};
            f32x4 acc1 = {0.0f, 0.0f, 0.0f, 0.0f};
            acc0 = __builtin_amdgcn_mfma_f32_16x16x32_bf16(A0c, Bc, acc0, 0, 0, 0);
            acc1 = __builtin_amdgcn_mfma_f32_16x16x32_bf16(A1c, Bc, acc1, 0, 0, 0);

            float S = 0.0f;
            #pragma unroll
            for (int rr = 0; rr < 4; ++rr) {
                const float h0 = acc0[rr] + cb0[rr];
                const float q0 = (h0 >= 0.0f) ? h0 : 0.1f * h0;
                S = fmaf(q0, cw0[rr], S);
                const float h1 = acc1[rr] + cb1[rr];
                const float q1 = (h1 >= 0.0f) ? h1 : 0.1f * h1;
                S = fmaf(q1, cw1[rr], S);
            }
            S += __shfl_xor(S, 16);
            S += __shfl_xor(S, 32);

            if (lgrp == 0 && rl0 < cn0) out[rowbase + R0] = S + b2k;

            k0 = k1; cn0 = cn1; rl0 = rl1; R0 = R1;
            A0c = A0n; A1c = A1n; Bc = Bn;
            tix = nxt;
        }
        __syncthreads();                                      // BAR E (fbf reuse)
    }
}

extern "C" void kernel_launch(void* const* d_in, const int* in_sizes, int n_in,
                              void* d_out, int out_size, void* d_ws, size_t ws_size,
                              hipStream_t stream) {
    const float* x  = (const float*)d_in[0];
    const float* a  = (const float*)d_in[1];
    const float* b  = (const float*)d_in[2];
    const float* W1 = (const float*)d_in[3];
    const float* b1 = (const float*)d_in[4];
    const float* W2 = (const float*)d_in[5];
    const float* b2 = (const float*)d_in[6];
    float* out = (float*)d_out;

    char* ws = (char*)d_ws;
    bf16x8* A0tab = (bf16x8*)ws;                       // 21*64*16B
    bf16x8* A1tab = A0tab + KK * 64;                   // 21*64*16B
    float* gcst  = (float*)(A1tab + KK * 64);          // 21*68*4B

    hipLaunchKernelGGL(prep_kernel, dim3(KK), dim3(64), 0, stream,
                       W1, b1, W2, b2, A0tab, A1tab, gcst);

    hipLaunchKernelGGL(fused_kernel, dim3(NN / ROWS), dim3(256), 0, stream,
                       x, a, b, A0tab, A1tab, gcst, out);
}

// Round 18
// 19.567 us; speedup vs baseline: 2.9398x; 2.9398x over previous
//
#include <hip/hip_runtime.h>
#include <hip/hip_bf16.h>

#define NN 262144
#define DD 32
#define HH 31
#define KK 21
#define ROWS 256                 // rows per block (2 half-row chunks per thread)
#define FSTRIDE 18               // u32 words per feats row (72 B)
#define CSTRIDE 68               // floats per k in const table {b1'[32],w2[32],b2,pad3}

typedef __attribute__((ext_vector_type(8))) short bf16x8;
typedef __attribute__((ext_vector_type(4))) float f32x4;
typedef __attribute__((ext_vector_type(2))) unsigned int u32x2;
typedef __attribute__((ext_vector_type(4))) unsigned int u32x4;

static __device__ __forceinline__ unsigned short f2bf(float f) {
    __hip_bfloat16 h = __float2bfloat16(f);      // round-to-nearest-even
    return __builtin_bit_cast(unsigned short, h);
}
// single-instruction packed f32->bf16 (RNE), lo -> bits[15:0]
static __device__ __forceinline__ unsigned cvtpk(float lo, float hi) {
    unsigned r;
    asm("v_cvt_pk_bf16_f32 %0, %1, %2" : "=v"(r) : "v"(lo), "v"(hi));
    return r;
}

// ---------------- Prep: fold a,b into weights; build tables ----------------
// A0/A1tab[k][lane]: bf16( a[d] * W1[k][d][e] )  (A = scaled W1^T fragments)
// gcst[k]: { b1'[32] = b1 + sum_d b[d]*W1[d][e], w2[32], b2, pad }
__global__ __launch_bounds__(64) void prep_kernel(
    const float* __restrict__ W1, const float* __restrict__ b1,
    const float* __restrict__ W2, const float* __restrict__ b2,
    const float* __restrict__ av, const float* __restrict__ bv,
    bf16x8* __restrict__ A0tab, bf16x8* __restrict__ A1tab,
    float* __restrict__ gcst)
{
    const int k = (int)blockIdx.x;
    const int lane = (int)threadIdx.x;
    const int lrow = lane & 15, lgrp = lane >> 4;
    const float* __restrict__ W1k = W1 + k * HH * HH;
    const int e0 = lrow, e1 = 16 + lrow;

    bf16x8 A0, A1;
    #pragma unroll
    for (int j = 0; j < 4; ++j) {
        const int d1 = 4 * lgrp + j;
        const int d2 = 16 + 4 * lgrp + j;
        A0[j]     = (short)f2bf(av[d1] * W1k[d1 * HH + e0]);
        A0[4 + j] = (d2 < HH) ? (short)f2bf(av[d2] * W1k[d2 * HH + e0]) : (short)0;
        A1[j]     = (e1 < HH) ? (short)f2bf(av[d1] * W1k[d1 * HH + e1]) : (short)0;
        A1[4 + j] = (e1 < HH && d2 < HH) ? (short)f2bf(av[d2] * W1k[d2 * HH + e1]) : (short)0;
    }
    A0tab[k * 64 + lane] = A0;
    A1tab[k * 64 + lane] = A1;

    for (int i = lane; i < CSTRIDE; i += 64) {
        float v = 0.0f;
        if (i < 32) {
            if (i < HH) {
                float s = b1[k * HH + i];
                for (int d = 0; d < HH; ++d) s = fmaf(bv[d], W1k[d * HH + i], s);
                v = s;
            }
        } else if (i < 64) {
            const int e = i - 32; if (e < HH) v = W2[k * HH + e];
        } else if (i == 64) v = b2[k];
        gcst[k * CSTRIDE + i] = v;
    }
}

// ---------------- Fused: sort + software-pipelined MFMA ----------------
__global__ __launch_bounds__(256, 4) void fused_kernel(
    const float* __restrict__ x,
    const bf16x8* __restrict__ A0tab, const bf16x8* __restrict__ A1tab,
    const float* __restrict__ gcst,
    float* __restrict__ out)
{
    __shared__ unsigned fbf[ROWS * FSTRIDE];                  // 18432 B
    __shared__ __align__(16) float scst[KK * CSTRIDE];        // 5712 B
    __shared__ float sedges[KK + 1];
    __shared__ int cnt[KK];
    __shared__ int rnk[KK];
    __shared__ int sbase[KK];
    __shared__ int tstart[KK + 1];
    __shared__ unsigned short sorted[ROWS];

    const int tid = (int)threadIdx.x;
    const int lane = tid & 63;
    const int wave = tid >> 6;
    const int rowbase = (int)blockIdx.x * ROWS;

    if (tid < KK) { cnt[tid] = 0; rnk[tid] = 0; }
    if (tid < KK + 1)
        sedges[tid] = (tid == KK) ? 1000.0f : (float)tid / 10.0f;  // IEEE j/10
    for (int i = tid; i < KK * CSTRIDE / 4; i += 256)
        ((f32x4*)scst)[i] = ((const f32x4*)gcst)[i];
    __syncthreads();                                          // BAR1

    // ---- Phase 1: pack raw x (bf16) into LDS; arithmetic bucket ----
    int kq[2] = {-1, -1};
    #pragma unroll
    for (int i = 0; i < 2; ++i) {
        const int c    = tid + 256 * i;
        const int row  = c >> 1;
        const int half = c & 1;
        const float4* __restrict__ p =
            reinterpret_cast<const float4*>(x) + (size_t)blockIdx.x * (ROWS * DD / 4) + c * 4;
        float4 cc[4];
        #pragma unroll
        for (int j = 0; j < 4; ++j) cc[j] = p[j];

        const float e16 = __shfl(cc[0].x, lane + 1);  // odd lane's elem0 = x[16]
        const float t = cc[0].x;

        if (half == 0) {
            // candidate = ceil(t*10)-1, verified +-1 against exact edges
            int kc = (int)ceilf(t * 10.0f) - 1;
            kc = (kc < 0) ? 0 : ((kc > 19) ? 19 : kc);
            const float elo = sedges[kc];
            const float ehi = sedges[kc + 1];
            int kk = kc;
            if (t <= elo) kk = kc - 1;
            else if (t > ehi) kk = kc + 1;
            if (t > 2.0f) kk = (t <= 1000.0f) ? 20 : -1;
            if (t <= 0.0f) kk = -1;
            kq[i] = kk;
            if (kk >= 0) atomicAdd(&cnt[kk], 1);
            else out[rowbase + row] = 0.0f;
        }

        // even: x[1..16] (e16 via shfl); odd: x[17..31], pad 0
        const float* cf = (const float*)cc;
        const float f15 = half ? 0.0f : e16;
        unsigned* __restrict__ frow = fbf + row * FSTRIDE + half * 8;
        #pragma unroll
        for (int s = 0; s < 7; ++s)
            frow[s] = cvtpk(cf[2 * s + 1], cf[2 * s + 2]);
        frow[7] = cvtpk(cf[15], f15);
    }
    __syncthreads();                                          // BAR2

    // ---- Phase 2: wave-parallel scan + scatter ----
    if (tid < 64) {
        const int j = tid;
        const int c0 = (j < KK) ? cnt[j] : 0;
        const int t0 = (j < KK) ? ((c0 + 15) >> 4) : 0;
        int sc = c0, st = t0;
        #pragma unroll
        for (int off = 1; off < 32; off <<= 1) {
            const int vc = __shfl_up(sc, off);
            const int vt = __shfl_up(st, off);
            if (j >= off) { sc += vc; st += vt; }
        }
        if (j < KK) { sbase[j] = sc - c0; tstart[j] = st - t0; }
        if (j == KK) tstart[KK] = st;
    }
    __syncthreads();                                          // BAR3
    #pragma unroll
    for (int i = 0; i < 2; ++i) {
        const int c = tid + 256 * i;
        if (!(c & 1) && kq[i] >= 0) {
            const int rr = atomicAdd(&rnk[kq[i]], 1);
            sorted[sbase[kq[i]] + rr] = (unsigned short)(c >> 1);
        }
    }
    __syncthreads();                                          // BAR4

    // ---- Phase 3: software-pipelined MFMA tiles ----
    const int lrow = lane & 15;
    const int lgrp = lane >> 4;

    const int NT = tstart[KK];
    const int ts_l = tstart[(lane <= KK) ? lane : KK];

    int tix = wave;
    int k0 = 0, cn0 = 0, rl0 = 0, R0 = 0;
    bf16x8 A0c = {}, A1c = {}, Bc = {};

    if (tix < NT) {
        const unsigned long long m = __ballot(ts_l <= tix);
        k0 = __builtin_amdgcn_readfirstlane(__popcll(m) - 1);
        cn0 = cnt[k0];
        rl0 = (tix - tstart[k0]) * 16 + lrow;
        R0 = sorted[sbase[k0] + ((rl0 < cn0) ? rl0 : 0)];
        const unsigned* __restrict__ fr = fbf + R0 * FSTRIDE;
        const u32x2 wlo = *(const u32x2*)(fr + 2 * lgrp);
        const u32x2 whi = *(const u32x2*)(fr + 8 + 2 * lgrp);
        u32x4 bw; bw[0] = wlo[0]; bw[1] = wlo[1]; bw[2] = whi[0]; bw[3] = whi[1];
        Bc = __builtin_bit_cast(bf16x8, bw);
        A0c = A0tab[k0 * 64 + lane];
        A1c = A1tab[k0 * 64 + lane];
    }

    while (tix < NT) {
        const int nxt = tix + 4;
        const int pt = (nxt < NT) ? nxt : tix;
        const unsigned long long m = __ballot(ts_l <= pt);
        const int k1 = __builtin_amdgcn_readfirstlane(__popcll(m) - 1);
        const int cn1 = cnt[k1];
        const int rl1 = (pt - tstart[k1]) * 16 + lrow;
        const int R1 = sorted[sbase[k1] + ((rl1 < cn1) ? rl1 : 0)];
        const unsigned* __restrict__ frn = fbf + R1 * FSTRIDE;
        const u32x2 nlo = *(const u32x2*)(frn + 2 * lgrp);
        const u32x2 nhi = *(const u32x2*)(frn + 8 + 2 * lgrp);
        u32x4 nw; nw[0] = nlo[0]; nw[1] = nlo[1]; nw[2] = nhi[0]; nw[3] = nhi[1];
        const bf16x8 Bn = __builtin_bit_cast(bf16x8, nw);
        const bf16x8 A0n = A0tab[k1 * 64 + lane];
        const bf16x8 A1n = A1tab[k1 * 64 + lane];

        const float* __restrict__ cp = scst + k0 * CSTRIDE;
        const f32x4 cb0 = *(const f32x4*)(cp + 4 * lgrp);
        const f32x4 cb1 = *(const f32x4*)(cp + 16 + 4 * lgrp);
        const f32x4 cw0 = *(const f32x4*)(cp + 32 + 4 * lgrp);
        const f32x4 cw1 = *(const f32x4*)(cp + 48 + 4 * lgrp);
        const float b2k = cp[64];

        f32x4 acc0 = {0.0f, 0.0f, 0.0f, 0.0f};
        f32x4 acc1 = {0.0f, 0.0f, 0.0f, 0.0f};
        acc0 = __builtin_amdgcn_mfma_f32_16x16x32_bf16(A0c, Bc, acc0, 0, 0, 0);
        acc1 = __builtin_amdgcn_mfma_f32_16x16x32_bf16(A1c, Bc, acc1, 0, 0, 0);

        float S = 0.0f;
        #pragma unroll
        for (int rr = 0; rr < 4; ++rr) {
            const float h0 = acc0[rr] + cb0[rr];
            const float q0 = fmaxf(h0, 0.1f * h0);   // == lrelu for both signs
            S = fmaf(q0, cw0[rr], S);
            const float h1 = acc1[rr] + cb1[rr];
            const float q1 = fmaxf(h1, 0.1f * h1);
            S = fmaf(q1, cw1[rr], S);
        }
        S += __shfl_xor(S, 16);
        S += __shfl_xor(S, 32);

        if (lgrp == 0 && rl0 < cn0) out[rowbase + R0] = S + b2k;

        k0 = k1; cn0 = cn1; rl0 = rl1; R0 = R1;
        A0c = A0n; A1c = A1n; Bc = Bn;
        tix = nxt;
    }
}

extern "C" void kernel_launch(void* const* d_in, const int* in_sizes, int n_in,
                              void* d_out, int out_size, void* d_ws, size_t ws_size,
                              hipStream_t stream) {
    const float* x  = (const float*)d_in[0];
    const float* a  = (const float*)d_in[1];
    const float* b  = (const float*)d_in[2];
    const float* W1 = (const float*)d_in[3];
    const float* b1 = (const float*)d_in[4];
    const float* W2 = (const float*)d_in[5];
    const float* b2 = (const float*)d_in[6];
    float* out = (float*)d_out;

    char* ws = (char*)d_ws;
    bf16x8* A0tab = (bf16x8*)ws;                       // 21*64*16B
    bf16x8* A1tab = A0tab + KK * 64;                   // 21*64*16B
    float* gcst  = (float*)(A1tab + KK * 64);          // 21*68*4B

    hipLaunchKernelGGL(prep_kernel, dim3(KK), dim3(64), 0, stream,
                       W1, b1, W2, b2, a, b, A0tab, A1tab, gcst);

    hipLaunchKernelGGL(fused_kernel, dim3(NN / ROWS), dim3(256), 0, stream,
                       x, A0tab, A1tab, gcst, out);
}

// Round 19
// 19.423 us; speedup vs baseline: 2.9615x; 1.0074x over previous
//
#include <hip/hip_runtime.h>
#include <hip/hip_bf16.h>

#define NN 262144
#define DD 32
#define HH 31
#define KK 21
#define ROWS 256                 // rows per block (2 half-row chunks per thread)
#define FSTRIDE 18               // u32 words per feats row (72 B)
#define CSTRIDE 68               // floats per k in const table {b1'[32],w2[32],b2,pad3}
#define MAXT 40                  // max tiles per block (<= 16 + 21)

typedef __attribute__((ext_vector_type(8))) short bf16x8;
typedef __attribute__((ext_vector_type(4))) float f32x4;
typedef __attribute__((ext_vector_type(2))) unsigned int u32x2;
typedef __attribute__((ext_vector_type(4))) unsigned int u32x4;

static __device__ __forceinline__ unsigned short f2bf(float f) {
    __hip_bfloat16 h = __float2bfloat16(f);      // round-to-nearest-even
    return __builtin_bit_cast(unsigned short, h);
}
// single-instruction packed f32->bf16 (RNE), lo -> bits[15:0]
static __device__ __forceinline__ unsigned cvtpk(float lo, float hi) {
    unsigned r;
    asm("v_cvt_pk_bf16_f32 %0, %1, %2" : "=v"(r) : "v"(lo), "v"(hi));
    return r;
}

// ---------------- Prep: fold a,b into weights; build tables ----------------
// A0/A1tab[k][lane]: bf16( a[d] * W1[k][d][e] )  (A = scaled W1^T fragments)
// gcst[k]: { b1'[32] = b1 + sum_d b[d]*W1[d][e], w2[32], b2, pad }
__global__ __launch_bounds__(64) void prep_kernel(
    const float* __restrict__ W1, const float* __restrict__ b1,
    const float* __restrict__ W2, const float* __restrict__ b2,
    const float* __restrict__ av, const float* __restrict__ bv,
    bf16x8* __restrict__ A0tab, bf16x8* __restrict__ A1tab,
    float* __restrict__ gcst)
{
    const int k = (int)blockIdx.x;
    const int lane = (int)threadIdx.x;
    const int lrow = lane & 15, lgrp = lane >> 4;
    const float* __restrict__ W1k = W1 + k * HH * HH;
    const int e0 = lrow, e1 = 16 + lrow;

    bf16x8 A0, A1;
    #pragma unroll
    for (int j = 0; j < 4; ++j) {
        const int d1 = 4 * lgrp + j;
        const int d2 = 16 + 4 * lgrp + j;
        A0[j]     = (short)f2bf(av[d1] * W1k[d1 * HH + e0]);
        A0[4 + j] = (d2 < HH) ? (short)f2bf(av[d2] * W1k[d2 * HH + e0]) : (short)0;
        A1[j]     = (e1 < HH) ? (short)f2bf(av[d1] * W1k[d1 * HH + e1]) : (short)0;
        A1[4 + j] = (e1 < HH && d2 < HH) ? (short)f2bf(av[d2] * W1k[d2 * HH + e1]) : (short)0;
    }
    A0tab[k * 64 + lane] = A0;
    A1tab[k * 64 + lane] = A1;

    for (int i = lane; i < CSTRIDE; i += 64) {
        float v = 0.0f;
        if (i < 32) {
            if (i < HH) {
                float s = b1[k * HH + i];
                for (int d = 0; d < HH; ++d) s = fmaf(bv[d], W1k[d * HH + i], s);
                v = s;
            }
        } else if (i < 64) {
            const int e = i - 32; if (e < HH) v = W2[k * HH + e];
        } else if (i == 64) v = b2[k];
        gcst[k * CSTRIDE + i] = v;
    }
}

// ---------------- Fused: sort + software-pipelined MFMA ----------------
__global__ __launch_bounds__(256, 4) void fused_kernel(
    const float* __restrict__ x,
    const bf16x8* __restrict__ A0tab, const bf16x8* __restrict__ A1tab,
    const float* __restrict__ gcst,
    float* __restrict__ out)
{
    __shared__ unsigned fbf[ROWS * FSTRIDE];                  // 18432 B
    __shared__ __align__(16) float scst[KK * CSTRIDE];        // 5712 B
    __shared__ float sedges[KK + 1];
    __shared__ int cnt[KK];
    __shared__ int rnk[KK];
    __shared__ int sbase[KK];
    __shared__ int tstart[KK + 1];
    __shared__ int tilek[MAXT];
    __shared__ unsigned short sorted[ROWS];

    const int tid = (int)threadIdx.x;
    const int lane = tid & 63;
    const int wave = tid >> 6;
    const int rowbase = (int)blockIdx.x * ROWS;

    if (tid < KK) { cnt[tid] = 0; rnk[tid] = 0; }
    if (tid < KK + 1)
        sedges[tid] = (tid == KK) ? 1000.0f : (float)tid / 10.0f;  // IEEE j/10
    for (int i = tid; i < KK * CSTRIDE / 4; i += 256)
        ((f32x4*)scst)[i] = ((const f32x4*)gcst)[i];
    __syncthreads();                                          // BAR1

    // ---- Phase 1: pack raw x (bf16) into LDS; arithmetic bucket ----
    int kq[2] = {-1, -1};
    #pragma unroll
    for (int i = 0; i < 2; ++i) {
        const int c    = tid + 256 * i;
        const int row  = c >> 1;
        const int half = c & 1;
        const float4* __restrict__ p =
            reinterpret_cast<const float4*>(x) + (size_t)blockIdx.x * (ROWS * DD / 4) + c * 4;
        float4 cc[4];
        #pragma unroll
        for (int j = 0; j < 4; ++j) cc[j] = p[j];

        const float e16 = __shfl(cc[0].x, lane + 1);  // odd lane's elem0 = x[16]
        const float t = cc[0].x;

        if (half == 0) {
            // candidate = ceil(t*10)-1, verified +-1 against exact edges
            int kc = (int)ceilf(t * 10.0f) - 1;
            kc = (kc < 0) ? 0 : ((kc > 19) ? 19 : kc);
            const float elo = sedges[kc];
            const float ehi = sedges[kc + 1];
            int kk = kc;
            if (t <= elo) kk = kc - 1;
            else if (t > ehi) kk = kc + 1;
            if (t > 2.0f) kk = (t <= 1000.0f) ? 20 : -1;
            if (t <= 0.0f) kk = -1;
            kq[i] = kk;
            if (kk >= 0) atomicAdd(&cnt[kk], 1);
            else out[rowbase + row] = 0.0f;
        }

        // even: x[1..16] (e16 via shfl); odd: x[17..31], pad 0
        const float* cf = (const float*)cc;
        const float f15 = half ? 0.0f : e16;
        unsigned* __restrict__ frow = fbf + row * FSTRIDE + half * 8;
        #pragma unroll
        for (int s = 0; s < 7; ++s)
            frow[s] = cvtpk(cf[2 * s + 1], cf[2 * s + 2]);
        frow[7] = cvtpk(cf[15], f15);
    }
    __syncthreads();                                          // BAR2

    // ---- Phase 2: wave-parallel scan + tile->k table + scatter ----
    if (tid < 64) {
        const int j = tid;
        const int c0 = (j < KK) ? cnt[j] : 0;
        const int t0 = (j < KK) ? ((c0 + 15) >> 4) : 0;
        int sc = c0, st = t0;
        #pragma unroll
        for (int off = 1; off < 32; off <<= 1) {
            const int vc = __shfl_up(sc, off);
            const int vt = __shfl_up(st, off);
            if (j >= off) { sc += vc; st += vt; }
        }
        if (j < KK) {
            sbase[j] = sc - c0;
            tstart[j] = st - t0;
            for (int t = st - t0; t < st; ++t) tilek[t] = j;   // tile -> bucket
        }
        if (j == KK) tstart[KK] = st;
    }
    __syncthreads();                                          // BAR3
    #pragma unroll
    for (int i = 0; i < 2; ++i) {
        const int c = tid + 256 * i;
        if (!(c & 1) && kq[i] >= 0) {
            const int rr = atomicAdd(&rnk[kq[i]], 1);
            sorted[sbase[kq[i]] + rr] = (unsigned short)(c >> 1);
        }
    }
    __syncthreads();                                          // BAR4

    // ---- Phase 3: software-pipelined MFMA tiles (bias as MFMA C-init) ----
    const int lrow = lane & 15;
    const int lgrp = lane >> 4;
    const int NT = tstart[KK];

    int tix = wave;
    int k0 = 0, cn0 = 0, rl0 = 0, R0 = 0;
    bf16x8 A0c = {}, A1c = {}, Bc = {};

    if (tix < NT) {
        k0 = __builtin_amdgcn_readfirstlane(tilek[tix]);
        cn0 = cnt[k0];
        rl0 = (tix - tstart[k0]) * 16 + lrow;
        R0 = sorted[sbase[k0] + min(rl0, cn0 - 1)];
        const unsigned* __restrict__ fr = fbf + R0 * FSTRIDE;
        const u32x2 wlo = *(const u32x2*)(fr + 2 * lgrp);
        const u32x2 whi = *(const u32x2*)(fr + 8 + 2 * lgrp);
        u32x4 bw; bw[0] = wlo[0]; bw[1] = wlo[1]; bw[2] = whi[0]; bw[3] = whi[1];
        Bc = __builtin_bit_cast(bf16x8, bw);
        A0c = A0tab[k0 * 64 + lane];
        A1c = A1tab[k0 * 64 + lane];
    }

    while (tix < NT) {
        const int nxt = tix + 4;
        const int pt = (nxt < NT) ? nxt : tix;
        const int k1 = __builtin_amdgcn_readfirstlane(tilek[pt]);
        const int cn1 = cnt[k1];
        const int rl1 = (pt - tstart[k1]) * 16 + lrow;
        const int R1 = sorted[sbase[k1] + min(rl1, cn1 - 1)];
        const unsigned* __restrict__ frn = fbf + R1 * FSTRIDE;
        const u32x2 nlo = *(const u32x2*)(frn + 2 * lgrp);
        const u32x2 nhi = *(const u32x2*)(frn + 8 + 2 * lgrp);
        u32x4 nw; nw[0] = nlo[0]; nw[1] = nlo[1]; nw[2] = nhi[0]; nw[3] = nhi[1];
        const bf16x8 Bn = __builtin_bit_cast(bf16x8, nw);
        const bf16x8 A0n = A0tab[k1 * 64 + lane];
        const bf16x8 A1n = A1tab[k1 * 64 + lane];

        const float* __restrict__ cp = scst + k0 * CSTRIDE;
        const f32x4 cb0 = *(const f32x4*)(cp + 4 * lgrp);
        const f32x4 cb1 = *(const f32x4*)(cp + 16 + 4 * lgrp);
        const f32x4 cw0 = *(const f32x4*)(cp + 32 + 4 * lgrp);
        const f32x4 cw1 = *(const f32x4*)(cp + 48 + 4 * lgrp);
        const float b2k = cp[64];

        // bias rides in as the MFMA C operand: h = b1' + A*B
        f32x4 acc0 = __builtin_amdgcn_mfma_f32_16x16x32_bf16(A0c, Bc, cb0, 0, 0, 0);
        f32x4 acc1 = __builtin_amdgcn_mfma_f32_16x16x32_bf16(A1c, Bc, cb1, 0, 0, 0);

        float S = 0.0f;
        #pragma unroll
        for (int rr = 0; rr < 4; ++rr) {
            const float q0 = fmaxf(acc0[rr], 0.1f * acc0[rr]);   // lrelu
            S = fmaf(q0, cw0[rr], S);
            const float q1 = fmaxf(acc1[rr], 0.1f * acc1[rr]);
            S = fmaf(q1, cw1[rr], S);
        }
        S += __shfl_xor(S, 16);
        S += __shfl_xor(S, 32);

        if (lgrp == 0 && rl0 < cn0) out[rowbase + R0] = S + b2k;

        k0 = k1; cn0 = cn1; rl0 = rl1; R0 = R1;
        A0c = A0n; A1c = A1n; Bc = Bn;
        tix = nxt;
    }
}

extern "C" void kernel_launch(void* const* d_in, const int* in_sizes, int n_in,
                              void* d_out, int out_size, void* d_ws, size_t ws_size,
                              hipStream_t stream) {
    const float* x  = (const float*)d_in[0];
    const float* a  = (const float*)d_in[1];
    const float* b  = (const float*)d_in[2];
    const float* W1 = (const float*)d_in[3];
    const float* b1 = (const float*)d_in[4];
    const float* W2 = (const float*)d_in[5];
    const float* b2 = (const float*)d_in[6];
    float* out = (float*)d_out;

    char* ws = (char*)d_ws;
    bf16x8* A0tab = (bf16x8*)ws;                       // 21*64*16B
    bf16x8* A1tab = A0tab + KK * 64;                   // 21*64*16B
    float* gcst  = (float*)(A1tab + KK * 64);          // 21*68*4B

    hipLaunchKernelGGL(prep_kernel, dim3(KK), dim3(64), 0, stream,
                       W1, b1, W2, b2, a, b, A0tab, A1tab, gcst);

    hipLaunchKernelGGL(fused_kernel, dim3(NN / ROWS), dim3(256), 0, stream,
                       x, A0tab, A1tab, gcst, out);
}